// Round 4
// baseline (47.250 us; speedup 1.0000x reference)
//
#include <hip/hip_runtime.h>
#include <hip/hip_bf16.h>

typedef __attribute__((ext_vector_type(8))) short bf16x8;
typedef __attribute__((ext_vector_type(16))) float f32x16;
typedef __attribute__((ext_vector_type(4))) unsigned int u32x4;

#define CC 128
#define KK 128
#define HH 56
#define WW 56
#define HW (HH * WW)

__device__ __forceinline__ unsigned short f2bf(float f) {
  unsigned int u = __builtin_bit_cast(unsigned int, f);
  u += 0x7FFFu + ((u >> 16) & 1u);
  return (unsigned short)(u >> 16);
}

// K1: kernel (K,C,3,3) f32 -> wt3[t(72)][f(4)][lane(64)][j(8)] bf16.
// t = ph*18 + rs*2 + s ; k = f*32+(lane&31) ; c = ph*32 + s*16 + (lane>>5)*8 + j
__global__ void wtrans_kernel(const float* __restrict__ kin,
                              unsigned short* __restrict__ wt3) {
  int idx = blockIdx.x * 256 + threadIdx.x;  // 147456 exact
  int j = idx & 7;
  int l = (idx >> 3) & 63;
  int f = (idx >> 9) & 3;
  int t = idx >> 11;  // 0..71
  int ph = t / 18;
  int st = t - ph * 18;
  int rs = st >> 1;
  int s = st & 1;
  int k = f * 32 + (l & 31);
  int c = ph * 32 + s * 16 + (l >> 5) * 8 + j;
  wt3[idx] = f2bf(kin[(k * CC + c) * 9 + rs]);
}

// K2: direct 3x3 conv, implicit GEMM, mfma_f32_32x32x16_bf16.
// Grid (28=14bh x 2bw, 16n), 256 thr (4 waves). Block tile: 128k x 4h x
// (bw? 24w : 32w). Waves (kp,sh): 64k (2 kfrags) x {2 or 1} sfrags (4h x 8w).
// LDS: ping-pong 2 x [6h][40w][4oct][16B] = 30 KB, oct-slot swizzled.
// Staging: T14 split (issue fp32 loads early, cvt+ds_write late), 1 barrier
// per 32-ch phase. A prefetched dist-1 from wt3 (coalesced 1KB frags).
__global__ __launch_bounds__(256, 3) void conv_kernel(
    const float* __restrict__ x, const unsigned short* __restrict__ wt3,
    float* __restrict__ out) {
  __shared__ __align__(16) unsigned char xs[2 * 15360];  // 30 KB

  const int tid = threadIdx.x;
  const int lane = tid & 63;
  const int wv = tid >> 6;    // 0..3
  const int bx = blockIdx.x;  // 0..27
  const int bh = bx >> 1;
  const int bw = bx & 1;
  const int n = blockIdx.y;
  const int r0 = bh * 4;

  const int p = lane & 31;
  const int dr = p >> 3;     // 0..3
  const int dw = p & 7;      // 0..7
  const int hi = lane >> 5;  // 0..1

  const int kp = wv >> 1;  // k half
  const int sh = wv & 1;   // spatial half
  const int ns = (bw & sh) ? 1 : 2;
  const int wshift = bw ? 18 : 0;               // input col = wl + wshift - 1
  const int wbase = sh * 16 + dw + (bw ? 14 : 0);  // B-read local col base

  // ---- per-iter staging geometry (ph-independent) ----
  // cell c = i*64+lane ; i = it*4+wv (i==15 unused). c -> (h, wl, slot),
  // stored oct = slot ^ (wl&3)  (swizzle lives in the SOURCE address).
  int it_off[4], it_ok[4], it_c[4];
#pragma unroll
  for (int it = 0; it < 4; ++it) {
    int i = it * 4 + wv;
    int c = i * 64 + lane;  // 0..1023
    int h = c / 160;        // 0..6 (6 only for skipped i==15)
    int rem = c - h * 160;
    int wl = rem >> 2;
    int oct = (rem & 3) ^ (wl & 3);
    int row = r0 - 1 + h;
    int col = wl + wshift - 1;
    it_c[it] = c;
    it_ok[it] = (i < 15) && (row >= 0) && (row < HH) && (col >= 0) && (col < WW);
    it_off[it] = oct * 8 * HW + row * WW + col;
  }
  const float* xn = x + (size_t)n * CC * HW;

  float sreg[32];
  auto stage_issue = [&](int ph) {
    const float* base = xn + ph * 32 * HW;
#pragma unroll
    for (int it = 0; it < 4; ++it) {
      const float* sp = base + it_off[it];
#pragma unroll
      for (int ci = 0; ci < 8; ++ci)
        sreg[it * 8 + ci] = it_ok[it] ? sp[ci * HW] : 0.f;
    }
  };
  auto stage_write = [&](unsigned char* buf) {
#pragma unroll
    for (int it = 0; it < 4; ++it) {
      if (it * 4 + wv < 15) {
        unsigned int q0 = (unsigned int)f2bf(sreg[it * 8 + 0]) |
                          ((unsigned int)f2bf(sreg[it * 8 + 1]) << 16);
        unsigned int q1 = (unsigned int)f2bf(sreg[it * 8 + 2]) |
                          ((unsigned int)f2bf(sreg[it * 8 + 3]) << 16);
        unsigned int q2 = (unsigned int)f2bf(sreg[it * 8 + 4]) |
                          ((unsigned int)f2bf(sreg[it * 8 + 5]) << 16);
        unsigned int q3 = (unsigned int)f2bf(sreg[it * 8 + 6]) |
                          ((unsigned int)f2bf(sreg[it * 8 + 7]) << 16);
        u32x4 qq = {q0, q1, q2, q3};
        *(u32x4*)(buf + it_c[it] * 16) = qq;
      }
    }
  };

  auto ldA = [&](int t, bf16x8* D) {
#pragma unroll
    for (int kfl = 0; kfl < 2; ++kfl)
      D[kfl] = *(const bf16x8*)(wt3 + ((t * 4 + kp * 2 + kfl) << 9) + lane * 8);
  };

  f32x16 acc[2][2] = {};  // [kfl][si]
  bf16x8 A[2][2];         // [parity][kfl]

  stage_issue(0);
  stage_write(xs);
  __syncthreads();
  ldA(0, A[0]);

#pragma unroll 1
  for (int ph = 0; ph < 4; ++ph) {
    unsigned char* cur = xs + (ph & 1) * 15360;
    unsigned char* nxt = xs + ((ph + 1) & 1) * 15360;
    if (ph < 3) stage_issue(ph + 1);
#pragma unroll
    for (int st = 0; st < 18; ++st) {
      const int rs = st >> 1;
      const int s = st & 1;
      const int fr = (rs * 11) >> 5;  // rs/3
      const int fs = rs - fr * 3;
      bf16x8 B[2];
#pragma unroll
      for (int si = 0; si < 2; ++si) {
        if (si < ns) {
          const int wl = wbase + si * 8 + fs;
          B[si] = *(const bf16x8*)(cur + (dr + fr) * 2560 + wl * 64 +
                                   (((s << 1) + hi) ^ (wl & 3)) * 16);
        }
      }
      const int t = ph * 18 + st;
      if (t < 71) ldA(t + 1, A[(st + 1) & 1]);
#pragma unroll
      for (int kfl = 0; kfl < 2; ++kfl)
#pragma unroll
        for (int si = 0; si < 2; ++si)
          if (si < ns)
            acc[kfl][si] = __builtin_amdgcn_mfma_f32_32x32x16_bf16(
                A[st & 1][kfl], B[si], acc[kfl][si], 0, 0, 0);
    }
    if (ph < 3) {
      stage_write(nxt);
      __syncthreads();
    }
  }

  // ---- epilogue: C/D col=lane&31 -> spatial; krow=(r&3)+8*(r>>2)+4*hi ----
#pragma unroll
  for (int kfl = 0; kfl < 2; ++kfl) {
#pragma unroll
    for (int si = 0; si < 2; ++si) {
      if (si < ns) {
        const int sg = bw * 4 + sh * 2 + si;
        float* op = out +
                    ((size_t)(n * KK + kp * 64 + kfl * 32 + (hi << 2)) * HH +
                     (r0 + dr)) * WW + sg * 8 + dw;
#pragma unroll
        for (int r = 0; r < 16; ++r) {
          const int ko = (r & 3) + ((r >> 2) << 3);
          op[(size_t)ko * HW] = acc[kfl][si][r];
        }
      }
    }
  }
}

extern "C" void kernel_launch(void* const* d_in, const int* in_sizes, int n_in,
                              void* d_out, int out_size, void* d_ws, size_t ws_size,
                              hipStream_t stream) {
  const float* x = (const float*)d_in[0];
  const float* kin = (const float*)d_in[1];
  float* out = (float*)d_out;
  unsigned short* wt3 = (unsigned short*)d_ws;  // 147456 bf16 = 288 KB

  hipLaunchKernelGGL(wtrans_kernel, dim3(576), dim3(256), 0, stream, kin, wt3);
  hipLaunchKernelGGL(conv_kernel, dim3(28, 16), dim3(256), 0, stream, x, wt3, out);
}